// Round 3
// baseline (129.313 us; speedup 1.0000x reference)
//
#include <hip/hip_runtime.h>
#include <hip/hip_bf16.h>

typedef __bf16 bf16x8 __attribute__((ext_vector_type(8)));
typedef __bf16 bf16x2 __attribute__((ext_vector_type(2)));
typedef float f32x4 __attribute__((ext_vector_type(4)));

#define NROWS 8192
#define HALF_N 4096
#define DIM 128
#define ROW_BYTES 256          /* 128 bf16 */
#define TINV 10.0f
#define C1 14.42695040888963f  /* (1/T) * log2(e) */
#define LN2 0.6931471805599453f
#define COL_SPLITS 8
#define ITERS 8                /* (NROWS/COL_SPLITS)/128 */

/* rn stored globally swizzled: 16B chunk kc of row r at r*256 + (kc^(r&7))*16.
   global_load_lds copies verbatim; fragment reads spread across banks. */
#define SWZ(r, kc) ((kc) ^ ((r) & 7))

// ---------------- kernel 1: row-normalize -> swizzled bf16; zero rowsum & out
__global__ __launch_bounds__(256) void k_normalize(
    const float* __restrict__ zi, const float* __restrict__ zj,
    char* __restrict__ rn, float* __restrict__ rowsum, float* __restrict__ out)
{
    const int row  = blockIdx.x * 4 + (threadIdx.x >> 6);
    const int lane = threadIdx.x & 63;
    const float* src = (row < HALF_N) ? (zi + (size_t)row * DIM)
                                      : (zj + (size_t)(row - HALF_N) * DIM);
    float2 v = *(const float2*)(src + lane * 2);
    float ss = v.x * v.x + v.y * v.y;
    #pragma unroll
    for (int m = 32; m >= 1; m >>= 1) ss += __shfl_xor(ss, m, 64);
    const float scale = 1.0f / fmaxf(sqrtf(ss), 1e-8f);
    bf16x2 o; o[0] = (__bf16)(v.x * scale); o[1] = (__bf16)(v.y * scale);
    char* dst = rn + (size_t)row * ROW_BYTES + SWZ(row, lane >> 2) * 16 + (lane & 3) * 4;
    *(bf16x2*)dst = o;
    if (blockIdx.x < 32) rowsum[blockIdx.x * 256 + threadIdx.x] = 0.0f;
    if (blockIdx.x == 0 && threadIdx.x == 0) out[0] = 0.0f;
}

// ---------------- kernel 2: sim GEMM + exp rowsum, double-buffered DMA ------
// 128x128 tile, K=128 one-shot. A-frags straight from global into registers.
// B tiles ping-pong through lds[2][32KB]; raw s_waitcnt vmcnt(8)+s_barrier
// keeps the next stage's DMA in flight across the barrier (never drain to 0
// except the final iteration, whose loads are 2 stages old).
__global__ __launch_bounds__(256) void k_simsum(
    const char* __restrict__ rn, float* __restrict__ rowsum)
{
    __shared__ char lds[2][128 * ROW_BYTES];   // 64 KB
    const int tid  = threadIdx.x;
    const int wave = tid >> 6;
    const int lane = tid & 63;
    const int tile_m = blockIdx.x * 128;
    const int w0 = wave & 1, w1 = wave >> 1;
    const int qrow = lane >> 4;
    const int lcol = lane & 15;
    const int col_base = blockIdx.y * (NROWS / COL_SPLITS);

    auto stage = [&](int it, int p) {
        const char* gB = rn + (size_t)(col_base + it * 128) * ROW_BYTES;
        #pragma unroll
        for (int i = 0; i < 8; ++i) {
            const int off = wave * 8192 + i * 1024;
            __builtin_amdgcn_global_load_lds(
                (const __attribute__((address_space(1))) void*)(gB + off + lane * 16),
                (__attribute__((address_space(3))) void*)(&lds[p][off]),
                16, 0, 0);
        }
    };

    stage(0, 0);                       // 8 outstanding

    // A fragments direct from global (rows tile_m+w1*64 .. +63, all K):
    // same swizzle arithmetic as LDS reads since tile_m,w1*64,mi*16 == 0 mod 8
    bf16x8 afrag[4][4];
    #pragma unroll
    for (int mi = 0; mi < 4; ++mi) {
        const int m = tile_m + w1 * 64 + mi * 16 + lcol;
        #pragma unroll
        for (int ks = 0; ks < 4; ++ks)
            afrag[mi][ks] = *(const bf16x8*)(rn + (size_t)m * ROW_BYTES
                                             + SWZ(m, ks * 4 + qrow) * 16);
    }                                  // +16 outstanding

    stage(1, 1);                       // +8 -> 32 outstanding

    float rsum[4][4];
    #pragma unroll
    for (int mi = 0; mi < 4; ++mi)
        #pragma unroll
        for (int r = 0; r < 4; ++r) rsum[mi][r] = 0.0f;

    #pragma unroll
    for (int it = 0; it < ITERS; ++it) {
        const int p = it & 1;
        // wait for OWN stage `it` (leave next stage's 8 loads in flight)
        if (it == ITERS - 1)
            asm volatile("s_waitcnt vmcnt(0)\n\ts_barrier" ::: "memory");
        else
            asm volatile("s_waitcnt vmcnt(8)\n\ts_barrier" ::: "memory");

        f32x4 acc[4][4];
        const f32x4 zero = {0.0f, 0.0f, 0.0f, 0.0f};
        #pragma unroll
        for (int mi = 0; mi < 4; ++mi)
            #pragma unroll
            for (int ni = 0; ni < 4; ++ni) acc[mi][ni] = zero;

        #pragma unroll
        for (int ks = 0; ks < 4; ++ks) {
            bf16x8 bfrag[4];
            #pragma unroll
            for (int ni = 0; ni < 4; ++ni) {
                const int n = w0 * 64 + ni * 16 + lcol;
                bfrag[ni] = *(const bf16x8*)(&lds[p][n * ROW_BYTES
                                             + SWZ(n, ks * 4 + qrow) * 16]);
            }
            #pragma unroll
            for (int mi = 0; mi < 4; ++mi)
                #pragma unroll
                for (int ni = 0; ni < 4; ++ni)
                    acc[mi][ni] = __builtin_amdgcn_mfma_f32_16x16x32_bf16(
                        afrag[mi][ks], bfrag[ni], acc[mi][ni], 0, 0, 0);
        }

        // all waves done reading lds[p]; refill it immediately so the DMA
        // overlaps the exp epilogue + next stage's compute
        asm volatile("s_barrier" ::: "memory");
        if (it + 2 < ITERS) stage(it + 2, p);

        #pragma unroll
        for (int mi = 0; mi < 4; ++mi)
            #pragma unroll
            for (int ni = 0; ni < 4; ++ni)
                #pragma unroll
                for (int r = 0; r < 4; ++r)
                    rsum[mi][r] += __builtin_amdgcn_exp2f(acc[mi][ni][r] * C1 - C1);
    }

    #pragma unroll
    for (int mi = 0; mi < 4; ++mi)
        #pragma unroll
        for (int r = 0; r < 4; ++r) {
            float v = rsum[mi][r];
            v += __shfl_xor(v, 1, 64);
            v += __shfl_xor(v, 2, 64);
            v += __shfl_xor(v, 4, 64);
            v += __shfl_xor(v, 8, 64);
            if (lcol == 0)
                atomicAdd(&rowsum[tile_m + w1 * 64 + mi * 16 + qrow * 4 + r], v);
        }
}

// ---------------- kernel 3: per-row loss + global reduce (merged) ----------
// loss_k = 1/T + ln(rowsum_k + exp((p_k-1)/T)) - p_k/T ; out = sum/8192
__global__ __launch_bounds__(256) void k_final(
    const char* __restrict__ rn, const float* __restrict__ rowsum,
    float* __restrict__ out)
{
    const int wave = threadIdx.x >> 6;
    const int lane = threadIdx.x & 63;
    float lsum = 0.0f;
    for (int i = 0; i < 32; ++i) {
        const int row     = blockIdx.x * 128 + wave * 32 + i;
        const int partner = (row + HALF_N) & (NROWS - 1);
        const bf16x2 a = *(const bf16x2*)(rn + (size_t)row * ROW_BYTES
                            + SWZ(row, lane >> 2) * 16 + (lane & 3) * 4);
        const bf16x2 b = *(const bf16x2*)(rn + (size_t)partner * ROW_BYTES
                            + SWZ(partner, lane >> 2) * 16 + (lane & 3) * 4);
        float p = (float)a[0] * (float)b[0] + (float)a[1] * (float)b[1];
        #pragma unroll
        for (int m = 32; m >= 1; m >>= 1) p += __shfl_xor(p, m, 64);
        if (lane == 0) {
            float s = rowsum[row] + __builtin_amdgcn_exp2f(p * C1 - C1);
            lsum += TINV + __builtin_amdgcn_logf(s) * LN2 - TINV * p;
        }
    }
    __shared__ float part[4];
    if (lane == 0) part[wave] = lsum;
    __syncthreads();
    if (threadIdx.x == 0)
        atomicAdd(out, (part[0] + part[1] + part[2] + part[3]) * (1.0f / (float)NROWS));
}

extern "C" void kernel_launch(void* const* d_in, const int* in_sizes, int n_in,
                              void* d_out, int out_size, void* d_ws, size_t ws_size,
                              hipStream_t stream)
{
    const float* zi = (const float*)d_in[0];
    const float* zj = (const float*)d_in[1];
    float* out = (float*)d_out;

    // ws: [0, 2MB) rn (swizzled bf16); [2MB, +32KB) rowsum f32[8192]
    char*  rn     = (char*)d_ws;
    float* rowsum = (float*)((char*)d_ws + (size_t)NROWS * ROW_BYTES);

    k_normalize<<<NROWS / 4, 256, 0, stream>>>(zi, zj, rn, rowsum, out);
    k_simsum<<<dim3(NROWS / 128, COL_SPLITS), 256, 0, stream>>>(rn, rowsum);
    k_final<<<NROWS / 128, 256, 0, stream>>>(rn, rowsum, out);
}

// Round 4
// 104.799 us; speedup vs baseline: 1.2339x; 1.2339x over previous
//
#include <hip/hip_runtime.h>
#include <hip/hip_bf16.h>

typedef __bf16 bf16x8 __attribute__((ext_vector_type(8)));
typedef __bf16 bf16x2 __attribute__((ext_vector_type(2)));
typedef float f32x4 __attribute__((ext_vector_type(4)));

#define NROWS 8192
#define HALF_N 4096
#define DIM 128
#define ROW_BYTES 256          /* 128 bf16 */
#define TINV 10.0f
#define C1 14.42695040888963f  /* (1/T) * log2(e) */
#define LN2 0.6931471805599453f
#define COL_SPLITS 8
#define COLS_PER (NROWS / COL_SPLITS)   /* 1024 */
#define ITERS (COLS_PER / 128)          /* 8 */
#define NBLOCKS (COL_SPLITS * (NROWS / 128))  /* 512 */

/* rn stored globally swizzled: 16B chunk kc of row r at r*256 + (kc^(r&7))*16.
   global_load_lds copies verbatim; LDS fragment reads spread over all banks. */
#define SWZ(r, kc) ((kc) ^ ((r) & 7))

// ------- kernel 1: row-normalize -> swizzled bf16; zero rowsum & done -------
__global__ __launch_bounds__(256) void k_normalize(
    const float* __restrict__ zi, const float* __restrict__ zj,
    char* __restrict__ rn, float* __restrict__ rowsum,
    unsigned int* __restrict__ done)
{
    const int wv   = threadIdx.x >> 6;
    const int lane = threadIdx.x & 63;
    #pragma unroll
    for (int i = 0; i < 4; ++i) {
        const int row = blockIdx.x * 16 + wv * 4 + i;
        const float* src = (row < HALF_N) ? (zi + (size_t)row * DIM)
                                          : (zj + (size_t)(row - HALF_N) * DIM);
        float2 v = *(const float2*)(src + lane * 2);
        float ss = v.x * v.x + v.y * v.y;
        #pragma unroll
        for (int m = 32; m >= 1; m >>= 1) ss += __shfl_xor(ss, m, 64);
        const float scale = 1.0f / fmaxf(sqrtf(ss), 1e-8f);
        bf16x2 o; o[0] = (__bf16)(v.x * scale); o[1] = (__bf16)(v.y * scale);
        char* dst = rn + (size_t)row * ROW_BYTES + SWZ(row, lane >> 2) * 16 + (lane & 3) * 4;
        *(bf16x2*)dst = o;
    }
    if (blockIdx.x < 32) rowsum[blockIdx.x * 256 + threadIdx.x] = 0.0f;
    if (blockIdx.x == 0 && threadIdx.x == 0) *done = 0u;
}

// ------- kernel 2: sim GEMM + exp rowsum + positive extraction + finalize ---
// 128x128 tile, K=128 one-shot. A-frags direct global->regs. B tiles ping-pong
// lds[2][32KB]; s_waitcnt vmcnt(8)+s_barrier keeps next stage's DMA in flight
// across the barrier. OUTER LOOP NOT UNROLLED (round-3 spill fix).
// Last block to finish (done-counter) computes the scalar loss.
__global__ __launch_bounds__(256) void k_simsum(
    const char* __restrict__ rn, float* __restrict__ rowsum,
    float* __restrict__ pbuf, unsigned int* __restrict__ done,
    float* __restrict__ out)
{
    __shared__ char lds[2][128 * ROW_BYTES];   // 64 KB
    const int tid  = threadIdx.x;
    const int wave = tid >> 6;
    const int lane = tid & 63;
    const int tile_m = blockIdx.x * 128;
    const int w0 = wave & 1, w1 = wave >> 1;
    const int qrow = lane >> 4;
    const int lcol = lane & 15;
    const int col_base = blockIdx.y * COLS_PER;
    // which col-iteration holds the positive diagonal for this row tile
    const int prel = (((tile_m + HALF_N) & (NROWS - 1)) - col_base);
    const int it_p = (prel >= 0 && prel < COLS_PER) ? (prel >> 7) : -1;

    auto stage = [&](int it2, int pp) {
        const char* g = rn + (size_t)(col_base + it2 * 128) * ROW_BYTES;
        #pragma unroll
        for (int i = 0; i < 8; ++i) {
            const int off = wave * 8192 + i * 1024;
            __builtin_amdgcn_global_load_lds(
                (const __attribute__((address_space(1))) void*)(g + off + lane * 16),
                (__attribute__((address_space(3))) void*)(&lds[pp][off]),
                16, 0, 0);
        }
    };

    stage(0, 0);

    // A fragments direct from global (swizzle matches since offsets are 0 mod 8)
    bf16x8 afrag[4][4];
    #pragma unroll
    for (int mi = 0; mi < 4; ++mi) {
        const int m = tile_m + w1 * 64 + mi * 16 + lcol;
        #pragma unroll
        for (int ks = 0; ks < 4; ++ks)
            afrag[mi][ks] = *(const bf16x8*)(rn + (size_t)m * ROW_BYTES
                                             + SWZ(m, ks * 4 + qrow) * 16);
    }

    stage(1, 1);

    float rsum[4][4];
    #pragma unroll
    for (int mi = 0; mi < 4; ++mi)
        #pragma unroll
        for (int r = 0; r < 4; ++r) rsum[mi][r] = 0.0f;

    #pragma unroll 1
    for (int it = 0; it < ITERS; ++it) {
        const int p = it & 1;
        if (it == ITERS - 1)
            asm volatile("s_waitcnt vmcnt(0)\n\ts_barrier" ::: "memory");
        else
            asm volatile("s_waitcnt vmcnt(8)\n\ts_barrier" ::: "memory");

        f32x4 acc[4][4];
        const f32x4 zero = {0.0f, 0.0f, 0.0f, 0.0f};
        #pragma unroll
        for (int mi = 0; mi < 4; ++mi)
            #pragma unroll
            for (int ni = 0; ni < 4; ++ni) acc[mi][ni] = zero;

        #pragma unroll
        for (int ks = 0; ks < 4; ++ks) {
            bf16x8 bfrag[4];
            #pragma unroll
            for (int ni = 0; ni < 4; ++ni) {
                const int n = w0 * 64 + ni * 16 + lcol;
                bfrag[ni] = *(const bf16x8*)(&lds[p][n * ROW_BYTES
                                             + SWZ(n, ks * 4 + qrow) * 16]);
            }
            #pragma unroll
            for (int mi = 0; mi < 4; ++mi)
                #pragma unroll
                for (int ni = 0; ni < 4; ++ni)
                    acc[mi][ni] = __builtin_amdgcn_mfma_f32_16x16x32_bf16(
                        afrag[mi][ks], bfrag[ni], acc[mi][ni], 0, 0, 0);
        }

        asm volatile("s_barrier" ::: "memory");   // all waves done reading lds[p]
        if (it + 2 < ITERS) stage(it + 2, p);     // refill flies over epilogue+next compute

        if (it == it_p) {   // extract positives sim[r, r+N mod 2N] from this tile
            #pragma unroll
            for (int mi = 0; mi < 4; ++mi) {
                const int rl = w1 * 64 + mi * 16 + qrow * 4;
                #pragma unroll
                for (int ni = 0; ni < 4; ++ni) {
                    const int cl = w0 * 64 + ni * 16 + lcol;
                    #pragma unroll
                    for (int rr = 0; rr < 4; ++rr)
                        if (cl == rl + rr)
                            __hip_atomic_store(&pbuf[tile_m + rl + rr], acc[mi][ni][rr],
                                               __ATOMIC_RELAXED, __HIP_MEMORY_SCOPE_AGENT);
                }
            }
        }

        #pragma unroll
        for (int mi = 0; mi < 4; ++mi)
            #pragma unroll
            for (int ni = 0; ni < 4; ++ni)
                #pragma unroll
                for (int r = 0; r < 4; ++r)
                    rsum[mi][r] += __builtin_amdgcn_exp2f(acc[mi][ni][r] * C1 - C1);
    }

    #pragma unroll
    for (int mi = 0; mi < 4; ++mi)
        #pragma unroll
        for (int r = 0; r < 4; ++r) {
            float v = rsum[mi][r];
            v += __shfl_xor(v, 1, 64);
            v += __shfl_xor(v, 2, 64);
            v += __shfl_xor(v, 4, 64);
            v += __shfl_xor(v, 8, 64);
            if (lcol == 0)
                atomicAdd(&rowsum[tile_m + w1 * 64 + mi * 16 + qrow * 4 + r], v);
        }

    // ---- last-block finalize ----
    __syncthreads();   // drains vmcnt: this block's atomics/stores complete
    __shared__ int is_last;
    if (tid == 0) {
        __threadfence();
        unsigned old = __hip_atomic_fetch_add(done, 1u, __ATOMIC_ACQ_REL,
                                              __HIP_MEMORY_SCOPE_AGENT);
        is_last = (old == NBLOCKS - 1);
    }
    __syncthreads();
    if (!is_last) return;
    __threadfence();

    float lsum = 0.0f;
    for (int r = tid; r < NROWS; r += 256) {
        float rs = __hip_atomic_load(&rowsum[r], __ATOMIC_RELAXED, __HIP_MEMORY_SCOPE_AGENT);
        float pv = __hip_atomic_load(&pbuf[r],   __ATOMIC_RELAXED, __HIP_MEMORY_SCOPE_AGENT);
        float S  = rs + __builtin_amdgcn_exp2f(pv * C1 - C1);
        lsum += TINV + __builtin_amdgcn_logf(S) * LN2 - TINV * pv;
    }
    #pragma unroll
    for (int m = 32; m >= 1; m >>= 1) lsum += __shfl_xor(lsum, m, 64);
    __shared__ float part[4];
    if (lane == 0) part[wave] = lsum;
    __syncthreads();
    if (tid == 0)
        out[0] = (part[0] + part[1] + part[2] + part[3]) * (1.0f / (float)NROWS);
}

extern "C" void kernel_launch(void* const* d_in, const int* in_sizes, int n_in,
                              void* d_out, int out_size, void* d_ws, size_t ws_size,
                              hipStream_t stream)
{
    const float* zi = (const float*)d_in[0];
    const float* zj = (const float*)d_in[1];
    float* out = (float*)d_out;

    // ws: [0,2MB) rn swizzled bf16; then rowsum f32[8192]; pbuf f32[8192]; done
    char*  rn     = (char*)d_ws;
    float* rowsum = (float*)((char*)d_ws + (size_t)NROWS * ROW_BYTES);
    float* pbuf   = rowsum + NROWS;
    unsigned int* done = (unsigned int*)(pbuf + NROWS);

    k_normalize<<<NROWS / 16, 256, 0, stream>>>(zi, zj, rn, rowsum, done);
    k_simsum<<<dim3(NROWS / 128, COL_SPLITS), 256, 0, stream>>>(rn, rowsum, pbuf, done, out);
}